// Round 6
// baseline (107.789 us; speedup 1.0000x reference)
//
#include <hip/hip_runtime.h>

// bf16 MFMA implicit GEMM for 3x3 valid conv + bias.
// R4 geometry (256 thr, 4-row blocks, 2 blocks/CU) + w-register prefetch:
// both x and w for chunk k+1 are loaded into registers during chunk k's MFMA
// loop, so the barrier-to-barrier staging window is pure ds_write (no vmcnt
// wait on L2/HBM inside it).
//
// x: [32,64,64,64] f32, w: [64,64,3,3] f32, b: [64] f32, out: [32,64,62,62] f32
// Per tap (r,s), per c-chunk of 16:  D[f][ow] += W[f][c] * X[c][ow]
// MFMA 32x32x16 bf16, A = w (m=f), B = x (n=ow)  ->  C/D col = lane&31 = ow.

#define N_  32
#define OH_ 62
#define OW_ 62

typedef __attribute__((ext_vector_type(8)))  short short8;
typedef __attribute__((ext_vector_type(16))) float float16;

__device__ __forceinline__ unsigned short f2bf(float v) {
    unsigned int u = __builtin_bit_cast(unsigned int, v);
    u += 0x7FFFu + ((u >> 16) & 1u);
    return (unsigned short)(u >> 16);
}
__device__ __forceinline__ unsigned int pack2(float a, float b) {
    return (unsigned int)f2bf(a) | ((unsigned int)f2bf(b) << 16);
}
__device__ __forceinline__ short8 bc(uint4 v) {
    return __builtin_bit_cast(short8, v);
}

// w [F][C][3][3] f32 -> wt bf16 [chunk4][tap9][half2][f64][j8]
__global__ __launch_bounds__(256) void wprep(const float* __restrict__ w,
                                             unsigned short* __restrict__ wt) {
    int tid  = blockIdx.x * 256 + threadIdx.x;   // 0..36863
    int j    = tid & 7;
    int f    = (tid >> 3) & 63;
    int half = (tid >> 9) & 1;
    int ct   = tid >> 10;                        // chunk*9 + tap
    int tap  = ct % 9;
    int chunk= ct / 9;
    wt[tid] = f2bf(w[(f * 64 + chunk * 16 + half * 8 + j) * 9 + tap]);
}

__global__ __launch_bounds__(256, 2) void conv_mfma(
    const float* __restrict__ x,
    const uint4* __restrict__ wt4,   // bf16, uint4 units of 8 values
    const float* __restrict__ b,
    float* __restrict__ out)
{
    // x: [row6][col66][half2] uint4 units, col-stride 3 u4 (48 B, conflict-free)
    __shared__ uint4 xl4[6 * 66 * 3];            // 19008 B
    // w: [tap9][f64][half2] uint4 units, f-stride 3 u4 (48 B)
    __shared__ uint4 wl4[9 * 64 * 3];            // 27648 B

    const int n    = blockIdx.x;
    const int oh0  = blockIdx.y * 4;
    const int t    = threadIdx.x;
    const int wv   = t >> 6;          // wave id = oh offset
    const int ln31 = t & 31;
    const int cgrp = (t >> 5) & 1;    // k-half of the wave
    const int oh   = oh0 + wv;

    const float* xnb = x + (size_t)n * 64 * 4096;

    float16 acc00 = {0}, acc01 = {0}, acc10 = {0}, acc11 = {0};

    // per-thread x gather coordinates: 768 (row,half,col) units / 256 thr
    int colv[3], halfv[3], rowv[3], rowg[3];
#pragma unroll
    for (int i = 0; i < 3; ++i) {
        int id = t + 256 * i;         // 0..767
        colv[i]  = id & 63;
        int rh   = id >> 6;           // 0..11
        halfv[i] = rh & 1;
        rowv[i]  = rh >> 1;           // 0..5
        int rg = oh0 + rowv[i]; if (rg > 63) rg = 63;
        rowg[i] = rg;
    }
    // per-thread w staging units: 1152 u4 / 256 thr -> 5 slots (last half-valid)
    int wf_[5], wh_[5], wtp_[5];
    bool wvld[5];
#pragma unroll
    for (int i = 0; i < 5; ++i) {
        int id = t + 256 * i;         // 0..1279
        wvld[i] = id < 1152;
        wf_[i]  = id & 63;
        wh_[i]  = (id >> 6) & 1;
        wtp_[i] = id >> 7;
    }

    float g[3][8];
    uint4 wg[5];

    // ---- prologue: gather chunk 0 (x and w) into registers ----
#pragma unroll
    for (int i = 0; i < 3; ++i) {
        const float* xp = xnb + (size_t)(halfv[i] * 8) * 4096 + rowg[i] * 64 + colv[i];
#pragma unroll
        for (int j = 0; j < 8; ++j) g[i][j] = xp[(size_t)j * 4096];
    }
#pragma unroll
    for (int i = 0; i < 5; ++i)
        if (wvld[i]) wg[i] = wt4[t + 256 * i];

    for (int chunk = 0; chunk < 4; ++chunk) {
        __syncthreads();   // previous chunk's LDS readers done

        // ---- staging window: pure ds_write (no global waits) ----
#pragma unroll
        for (int i = 0; i < 3; ++i) {
            uint4 pv = { pack2(g[i][0], g[i][1]), pack2(g[i][2], g[i][3]),
                         pack2(g[i][4], g[i][5]), pack2(g[i][6], g[i][7]) };
            xl4[(rowv[i] * 66 + colv[i]) * 3 + halfv[i]] = pv;
        }
#pragma unroll
        for (int i = 0; i < 5; ++i)
            if (wvld[i]) wl4[(wtp_[i] * 64 + wf_[i]) * 3 + wh_[i]] = wg[i];
        __syncthreads();

        // ---- issue next chunk's gathers NOW; they drain during the MFMA loop ----
        if (chunk < 3) {
            const int c0n = (chunk + 1) * 16;
#pragma unroll
            for (int i = 0; i < 3; ++i) {
                const float* xp = xnb + (size_t)(c0n + halfv[i] * 8) * 4096
                                      + rowg[i] * 64 + colv[i];
#pragma unroll
                for (int j = 0; j < 8; ++j) g[i][j] = xp[(size_t)j * 4096];
            }
#pragma unroll
            for (int i = 0; i < 5; ++i)
                if (wvld[i]) wg[i] = wt4[(chunk + 1) * 1152 + t + 256 * i];
        }

        // ---- 9 taps x 2x2 MFMA, frags via ds_read_b128 (no global ops here) ----
#pragma unroll
        for (int r = 0; r < 3; ++r) {
            const int xrow = wv + r;
#pragma unroll
            for (int s = 0; s < 3; ++s) {
                const int tap = r * 3 + s;
                short8 a0 = bc(wl4[(tap * 64 + ln31)      * 3 + cgrp]);
                short8 a1 = bc(wl4[(tap * 64 + ln31 + 32) * 3 + cgrp]);
                short8 b0 = bc(xl4[(xrow * 66 + s + ln31)      * 3 + cgrp]);
                short8 b1 = bc(xl4[(xrow * 66 + s + ln31 + 32) * 3 + cgrp]);
                acc00 = __builtin_amdgcn_mfma_f32_32x32x16_bf16(a0, b0, acc00, 0, 0, 0);
                acc01 = __builtin_amdgcn_mfma_f32_32x32x16_bf16(a0, b1, acc01, 0, 0, 0);
                acc10 = __builtin_amdgcn_mfma_f32_32x32x16_bf16(a1, b0, acc10, 0, 0, 0);
                acc11 = __builtin_amdgcn_mfma_f32_32x32x16_bf16(a1, b1, acc11, 0, 0, 0);
            }
        }
    }

    // ---- epilogue: C/D row = (reg&3)+8*(reg>>2)+4*(lane>>5), col = lane&31 = ow ----
    if (oh < OH_) {
#pragma unroll
        for (int r = 0; r < 16; ++r) {
            int fr = (r & 3) + 8 * (r >> 2) + 4 * cgrp;
            float b0v = b[fr];
            float b1v = b[fr + 32];
            float* o0 = out + (((size_t)n * 64 + fr)      * OH_ + oh) * OW_;
            float* o1 = out + (((size_t)n * 64 + fr + 32) * OH_ + oh) * OW_;
            o0[ln31] = acc00[r] + b0v;
            o1[ln31] = acc10[r] + b1v;
            if (ln31 < 30) {
                o0[32 + ln31] = acc01[r] + b0v;
                o1[32 + ln31] = acc11[r] + b1v;
            }
        }
    }
}

extern "C" void kernel_launch(void* const* d_in, const int* in_sizes, int n_in,
                              void* d_out, int out_size, void* d_ws, size_t ws_size,
                              hipStream_t stream)
{
    const float* x = (const float*)d_in[0];
    const float* w = (const float*)d_in[1];
    const float* b = (const float*)d_in[2];
    float* out = (float*)d_out;
    unsigned short* wt = (unsigned short*)d_ws;   // 36864 bf16 = 73728 B

    wprep<<<144, 256, 0, stream>>>(w, wt);
    dim3 grid(N_, 16);                            // 32 images x 16 oh-blocks
    conv_mfma<<<grid, 256, 0, stream>>>(x, (const uint4*)wt, b, out);
}

// Round 7
// 95.348 us; speedup vs baseline: 1.1305x; 1.1305x over previous
//
#include <hip/hip_runtime.h>

// bf16 MFMA implicit GEMM for 3x3 valid conv + bias — pipelined-gather edition.
// (R4 configuration — best measured: 93.4 us total. R5/R6 variants regressed.)
// x: [32,64,64,64] f32, w: [64,64,3,3] f32, b: [64] f32, out: [32,64,62,62] f32
//
// Per tap (r,s), per c-chunk of 16:  D[f][ow] += W[f][c] * X[c][ow]
// MFMA 32x32x16 bf16, A = w (m=f), B = x (n=ow)  ->  C/D col = lane&31 = ow.
// Block = 256 thr = 4 waves = (n, oh0..oh0+3); wave tile 64f x 64ow (2x2 MFMAs).
// Grid = 512 blocks = 2 blocks/CU; x gathers for chunk k+1 issued before the
// MFMA loop so their ~900-cyc HBM latency drains under LDS/MFMA work.

#define N_  32
#define OH_ 62
#define OW_ 62

typedef __attribute__((ext_vector_type(8)))  short short8;
typedef __attribute__((ext_vector_type(16))) float float16;

__device__ __forceinline__ unsigned short f2bf(float v) {
    unsigned int u = __builtin_bit_cast(unsigned int, v);
    u += 0x7FFFu + ((u >> 16) & 1u);
    return (unsigned short)(u >> 16);
}
__device__ __forceinline__ unsigned int pack2(float a, float b) {
    return (unsigned int)f2bf(a) | ((unsigned int)f2bf(b) << 16);
}
__device__ __forceinline__ short8 bc(uint4 v) {
    return __builtin_bit_cast(short8, v);
}

// w [F][C][3][3] f32 -> wt bf16 [chunk4][tap9][half2][f64][j8]
__global__ __launch_bounds__(256) void wprep(const float* __restrict__ w,
                                             unsigned short* __restrict__ wt) {
    int tid  = blockIdx.x * 256 + threadIdx.x;   // 0..36863
    int j    = tid & 7;
    int f    = (tid >> 3) & 63;
    int half = (tid >> 9) & 1;
    int ct   = tid >> 10;                        // chunk*9 + tap
    int tap  = ct % 9;
    int chunk= ct / 9;
    wt[tid] = f2bf(w[(f * 64 + chunk * 16 + half * 8 + j) * 9 + tap]);
}

__global__ __launch_bounds__(256, 2) void conv_mfma(
    const float* __restrict__ x,
    const uint4* __restrict__ wt4,   // bf16, uint4 units of 8 values
    const float* __restrict__ b,
    float* __restrict__ out)
{
    // x: [row6][col66][half2] uint4 units, col-stride 3 u4 (48 B, conflict-free)
    __shared__ uint4 xl4[6 * 66 * 3];            // 19008 B
    // w: [tap9][f64][half2] uint4 units, f-stride 3 u4 (48 B)
    __shared__ uint4 wl4[9 * 64 * 3];            // 27648 B

    const int n    = blockIdx.x;
    const int oh0  = blockIdx.y * 4;
    const int t    = threadIdx.x;
    const int wv   = t >> 6;          // wave id = oh offset
    const int ln31 = t & 31;
    const int cgrp = (t >> 5) & 1;    // k-half of the wave
    const int oh   = oh0 + wv;

    const float* xnb = x + (size_t)n * 64 * 4096;

    float16 acc00 = {0}, acc01 = {0}, acc10 = {0}, acc11 = {0};

    // per-thread gather coordinates: 3 (row, c-half) slices, 64-lane col runs
    int colv[3], halfv[3], rowv[3], rowg[3];
#pragma unroll
    for (int i = 0; i < 3; ++i) {
        int id = t + 256 * i;         // 0..767
        colv[i]  = id & 63;
        int rh   = id >> 6;           // 0..11
        halfv[i] = rh & 1;
        rowv[i]  = rh >> 1;           // 0..5
        int rg = oh0 + rowv[i]; if (rg > 63) rg = 63;
        rowg[i] = rg;
    }

    float g[3][8];
    // ---- gather chunk 0 (exposed once) ----
#pragma unroll
    for (int i = 0; i < 3; ++i) {
        const float* xp = xnb + (size_t)(halfv[i] * 8) * 4096 + rowg[i] * 64 + colv[i];
#pragma unroll
        for (int j = 0; j < 8; ++j) g[i][j] = xp[(size_t)j * 4096];
    }

    for (int chunk = 0; chunk < 4; ++chunk) {
        __syncthreads();   // previous chunk's LDS readers done

        // ---- pack current gather regs -> LDS (b128 writes) ----
#pragma unroll
        for (int i = 0; i < 3; ++i) {
            uint4 pv = { pack2(g[i][0], g[i][1]), pack2(g[i][2], g[i][3]),
                         pack2(g[i][4], g[i][5]), pack2(g[i][6], g[i][7]) };
            xl4[(rowv[i] * 66 + colv[i]) * 3 + halfv[i]] = pv;
        }

        // ---- stage w chunk: straight uint4 copy (L2-resident after chunk 0) ----
        {
            const uint4* wc = wt4 + chunk * 1152;
#pragma unroll
            for (int i = 0; i < 5; ++i) {
                int id = t + 256 * i;        // 0..1279
                if (id < 1152) {
                    int f    = id & 63;
                    int half = (id >> 6) & 1;
                    int tap  = id >> 7;
                    wl4[(tap * 64 + f) * 3 + half] = wc[id];
                }
            }
        }
        __syncthreads();

        // ---- issue next chunk's gather NOW; it drains during the MFMA loop ----
        if (chunk < 3) {
            const int c0n = (chunk + 1) * 16;
#pragma unroll
            for (int i = 0; i < 3; ++i) {
                const float* xp = xnb + (size_t)(c0n + halfv[i] * 8) * 4096
                                      + rowg[i] * 64 + colv[i];
#pragma unroll
                for (int j = 0; j < 8; ++j) g[i][j] = xp[(size_t)j * 4096];
            }
        }

        // ---- 9 taps x 2x2 MFMA, frags via ds_read_b128 (no vmcnt ops here) ----
#pragma unroll
        for (int r = 0; r < 3; ++r) {
            const int xrow = wv + r;
#pragma unroll
            for (int s = 0; s < 3; ++s) {
                const int tap = r * 3 + s;
                short8 a0 = bc(wl4[(tap * 64 + ln31)      * 3 + cgrp]);
                short8 a1 = bc(wl4[(tap * 64 + ln31 + 32) * 3 + cgrp]);
                short8 b0 = bc(xl4[(xrow * 66 + s + ln31)      * 3 + cgrp]);
                short8 b1 = bc(xl4[(xrow * 66 + s + ln31 + 32) * 3 + cgrp]);
                acc00 = __builtin_amdgcn_mfma_f32_32x32x16_bf16(a0, b0, acc00, 0, 0, 0);
                acc01 = __builtin_amdgcn_mfma_f32_32x32x16_bf16(a0, b1, acc01, 0, 0, 0);
                acc10 = __builtin_amdgcn_mfma_f32_32x32x16_bf16(a1, b0, acc10, 0, 0, 0);
                acc11 = __builtin_amdgcn_mfma_f32_32x32x16_bf16(a1, b1, acc11, 0, 0, 0);
            }
        }
    }

    // ---- epilogue: C/D row = (reg&3)+8*(reg>>2)+4*(lane>>5), col = lane&31 = ow ----
    if (oh < OH_) {
#pragma unroll
        for (int r = 0; r < 16; ++r) {
            int fr = (r & 3) + 8 * (r >> 2) + 4 * cgrp;
            float b0v = b[fr];
            float b1v = b[fr + 32];
            float* o0 = out + (((size_t)n * 64 + fr)      * OH_ + oh) * OW_;
            float* o1 = out + (((size_t)n * 64 + fr + 32) * OH_ + oh) * OW_;
            o0[ln31] = acc00[r] + b0v;
            o1[ln31] = acc10[r] + b1v;
            if (ln31 < 30) {
                o0[32 + ln31] = acc01[r] + b0v;
                o1[32 + ln31] = acc11[r] + b1v;
            }
        }
    }
}

extern "C" void kernel_launch(void* const* d_in, const int* in_sizes, int n_in,
                              void* d_out, int out_size, void* d_ws, size_t ws_size,
                              hipStream_t stream)
{
    const float* x = (const float*)d_in[0];
    const float* w = (const float*)d_in[1];
    const float* b = (const float*)d_in[2];
    float* out = (float*)d_out;
    unsigned short* wt = (unsigned short*)d_ws;   // 36864 bf16 = 73728 B

    wprep<<<144, 256, 0, stream>>>(w, wt);
    dim3 grid(N_, 16);                            // 32 images x 16 oh-blocks
    conv_mfma<<<grid, 256, 0, stream>>>(x, (const uint4*)wt, b, out);
}